// Round 22
// baseline (17.489 us; speedup 1.0000x reference)
//
#include <hip/hip_runtime.h>
#include <math.h>

// Duhamel layer == per-channel causal FIR, h[q] = (1/wD) r^q sin(q*theta).
// Exact one-stream form: e[k] = (x[k] - g^W x[k-W])/wD;  Z = g Z + e;  y = Im Z.
// r15 structure + SPLIT-BARRIER STAGE (counted-wait, T4-style):
//   per thread: issue 4 stage loads (A=[0,976) quads, B=[976,2000)) ->
//   constants under load latency -> ds_write A (auto vmcnt(2), B stays in
//   flight) -> lgkmcnt(0)+raw s_barrier -> halo (reads A only) -> ds_write B
//   -> lgkmcnt(0)+raw s_barrier -> sub-rounds.  No full vmcnt(0) drain.
//   Geometry = r15: block=(batch,4096-chunk), wave o = channel o, 32 KB tile,
//   per-channel halo, private 8 KB ybuf, 256 blocks = 1/CU, one generation.

#define N_SAMP  65536
#define NB      16
#define NO      8
#define NT      512
#define LBLK    4096          // outputs per block per channel
#define LOOKB   3904          // ch0 halo 2048 + 1844 rounded to mult 32
#define TQ      2000          // tile quads (8000 floats = 32 KB)

constexpr int CW[NO]  = {1844, 1317, 1024, 768, 576, 419, 307, 230};
// per-lane halo samples (mult of 4): alpha*64*hseg >= 5.1 per channel
constexpr int CHS[NO] = {32, 24, 20, 16, 12, 8, 8, 4};

// XOR quad swizzle (involution within 8-quad groups): breaks stride-bank
// alignment of per-lane quad access.
__device__ __forceinline__ int P(int q) { return q ^ ((q >> 3) & 7); }

__device__ __forceinline__ float rfl(float x) {
    return __int_as_float(__builtin_amdgcn_readfirstlane(__float_as_int(x)));
}

template<int O>
__device__ __forceinline__ void duh_wave(const float* __restrict__ lw,
                                         const float* __restrict__ xb,
                                         float* __restrict__ out,
                                         float* __restrict__ tile,
                                         float* __restrict__ yw,   // 8KB slice
                                         int b, int n0, int t, int lane)
{
    constexpr int W  = CW[O];
    constexpr int Wu = (W + 3) & ~3;
    constexpr int E  = Wu - W;               // 0..3 intra-quad shift
    constexpr int QW = Wu / 4;               // delayed quad offset
    constexpr int HS = CHS[O];               // halo samples per lane
    constexpr int HQ = HS / 4;               // halo quads per lane

    const int tstart = n0 - LOOKB;

    // ---- issue ALL staging loads first (A oldest, B stays in flight) -------
    auto ldg = [&](int k) -> float4 {
        const int g0 = tstart + 4 * k;       // mult of 4
        float4 v;
        if (g0 >= 0 && g0 + 3 < N_SAMP) {
            v = *(const float4*)(xb + g0);
        } else {
            v.x = (g0 + 0 >= 0 && g0 + 0 < N_SAMP) ? xb[g0 + 0] : 0.0f;
            v.y = (g0 + 1 >= 0 && g0 + 1 < N_SAMP) ? xb[g0 + 1] : 0.0f;
            v.z = (g0 + 2 >= 0 && g0 + 2 < N_SAMP) ? xb[g0 + 2] : 0.0f;
            v.w = (g0 + 3 >= 0 && g0 + 3 < N_SAMP) ? xb[g0 + 3] : 0.0f;
        }
        return v;
    };
    const bool hasA1 = (t < 464);            // region A = 976 quads
    const float4 vA0 = ldg(t);
    float4 vA1;
    if (hasA1) vA1 = ldg(512 + t);
    const float4 vB0 = ldg(976 + t);         // region B = 1024 quads
    const float4 vB1 = ldg(1488 + t);

    // ---- per-wave channel constants (overlap the load latency) -------------
    const float omf  = fminf(fmaxf(__expf(lw[O]), 0.01f), 1000.0f);
    const float omD  = omf * 0.99874921777190895f;    // sqrt(1-0.05^2)
    const float th   = omD * 0.01f;
    const float alph = 0.0005f * omf;
    const float r1   = __expf(-alph);
    const float gr = rfl(r1 * __cosf(th)), gi = rfl(r1 * __sinf(th));   // g
    const float rW   = __expf(-alph * (float)W);
    const float aW   = th * (float)W;
    const float binv = 1.0f / omD;
    const float c1   = rfl(binv);
    const float c2   = rfl(binv * rW * __cosf(aW));    //  binv*Re g^W
    const float cei  = rfl(-binv * rW * __sinf(aW));   // -binv*Im g^W

    float g2r_ = gr*gr - gi*gi,         g2i_ = 2.f*gr*gi;
    float g3r_ = g2r_*gr - g2i_*gi,     g3i_ = g2r_*gi + g2i_*gr;
    float g4r_ = g2r_*g2r_ - g2i_*g2i_, g4i_ = 2.f*g2r_*g2i_;
    const float G2r = rfl(g2r_), G2i = rfl(g2i_);
    const float G3r = rfl(g3r_), G3i = rfl(g3i_);
    const float G4r = rfl(g4r_), G4i = rfl(g4i_);

    // Mo[k] = g^(32*2^k) k=0..6  (out scan; Mo[6] = g^2048 carry multiplier)
    float Mor[7], Moi[7];
    {
        const float rl = __expf(-alph * 32.f);
        const float al = th * 32.f;
        float pr = rl * __cosf(al), pq = rl * __sinf(al);
#pragma unroll
        for (int k = 0; k < 7; ++k) {
            Mor[k] = rfl(pr); Moi[k] = rfl(pq);
            const float nr = pr*pr - pq*pq, ni = 2.f*pr*pq;
            pr = nr; pq = ni;
        }
    }
    // Mh[k] = g^(HS*2^k) k=0..5  (halo scan)
    float Mhr[6], Mhi[6];
    {
        const float rl = __expf(-alph * (float)HS);
        const float al = th * (float)HS;
        float pr = rl * __cosf(al), pq = rl * __sinf(al);
#pragma unroll
        for (int k = 0; k < 6; ++k) {
            Mhr[k] = rfl(pr); Mhi[k] = rfl(pq);
            const float nr = pr*pr - pq*pq, ni = 2.f*pr*pq;
            pr = nr; pq = ni;
        }
    }
    // pl = g^(32*lane)
    float plr = 1.f, pli = 0.f;
#pragma unroll
    for (int k = 0; k < 6; ++k) {
        if ((lane >> k) & 1) {
            const float nr = plr*Mor[k] - pli*Moi[k];
            const float ni = plr*Moi[k] + pli*Mor[k];
            plr = nr; pli = ni;
        }
    }

    // ---- write region A (compiler waits vmcnt for A regs only), barrier ----
    *(float4*)&tile[4 * P(t)] = vA0;
    if (hasA1) *(float4*)&tile[4 * P(512 + t)] = vA1;
    asm volatile("s_waitcnt lgkmcnt(0)" ::: "memory");
    __builtin_amdgcn_s_barrier();            // region A visible; B in flight

#define LDQ(q) (*(const float4*)&tile[4 * P(q)])
#define DSEL(e0,e1,e2,e3,d0,dn)                                              \
    if constexpr (E == 0)      { e0=d0.x; e1=d0.y; e2=d0.z; e3=d0.w; }       \
    else if constexpr (E == 1) { e0=d0.y; e1=d0.z; e2=d0.w; e3=dn.x; }       \
    else if constexpr (E == 2) { e0=d0.z; e1=d0.w; e2=dn.x; e3=dn.y; }       \
    else                       { e0=d0.w; e1=dn.x; e2=dn.y; e3=dn.z; }
#define STEP(xa, xc)                                              \
    {                                                             \
        const float er = fmaf(-c2, (xc), c1 * (xa));              \
        const float ei = cei * (xc);                              \
        const float nr = fmaf(gr, Br, fmaf(-gi, Bi, er));         \
        const float ni = fmaf(gi, Br, fmaf( gr, Bi, ei));         \
        Br = nr; Bi = ni;                                         \
    }

    // ---------------- halo: HS samples/lane (reads region A ONLY) -----------
    // q-range: q1 in [976-16HS, 976), q2 = q1 - QW >= 3   -> all < 976.
    float Cr, Ci;
    {
        float Br = 0.f, Bi = 0.f;
        const int q1 = 976 - 16 * HS + HQ * lane;
        const int q2 = q1 - QW;
        float4 d0 = LDQ(q2);
#pragma unroll
        for (int m = 0; m < HQ; ++m) {
            const float4 s1 = LDQ(q1 + m);
            const float4 dn = LDQ(q2 + m + 1);
            float e0, e1, e2, e3;
            DSEL(e0, e1, e2, e3, d0, dn);
            STEP(s1.x, e0); STEP(s1.y, e1); STEP(s1.z, e2); STEP(s1.w, e3);
            d0 = dn;
        }
        float Sr = Br, Si = Bi;
#pragma unroll
        for (int k = 0; k < 6; ++k) {
            const int d = 1 << k;
            const float ur = __shfl_up(Sr, d, 64);
            const float ui = __shfl_up(Si, d, 64);
            if (lane >= d) {
                const float nr = fmaf(Mhr[k], ur, fmaf(-Mhi[k], ui, Sr));
                const float ni = fmaf(Mhr[k], ui, fmaf( Mhi[k], ur, Si));
                Sr = nr; Si = ni;
            }
        }
        Cr = rfl(__shfl(Sr, 63, 64));       // exact state at n0 (zero-seeded)
        Ci = rfl(__shfl(Si, 63, 64));
    }

    // ---- write region B (auto-waits B loads), barrier 2 --------------------
    *(float4*)&tile[4 * P(976 + t)]  = vB0;
    *(float4*)&tile[4 * P(1488 + t)] = vB1;
    asm volatile("s_waitcnt lgkmcnt(0)" ::: "memory");
    __builtin_amdgcn_s_barrier();            // full tile visible

    // ---------------- 2 out sub-rounds x 2048 samples -----------------------
#pragma unroll
    for (int s = 0; s < 2; ++s) {
        const int q1 = 976 + 512 * s + 8 * lane;
        const int q2 = q1 - QW;

        float4 lz[8];
        float Br = 0.f, Bi = 0.f;
        float4 d0 = LDQ(q2);
#pragma unroll
        for (int m = 0; m < 8; ++m) {
            const float4 s1 = LDQ(q1 + m);
            const float4 dn = LDQ(q2 + m + 1);
            float e0, e1, e2, e3;
            DSEL(e0, e1, e2, e3, d0, dn);
            float4 lq;
            STEP(s1.x, e0); lq.x = Bi;
            STEP(s1.y, e1); lq.y = Bi;
            STEP(s1.z, e2); lq.z = Bi;
            STEP(s1.w, e3); lq.w = Bi;
            lz[m] = lq;
            d0 = dn;
        }

        // wave inclusive affine scan (segment mult g^32)
        float Sr = Br, Si = Bi;
#pragma unroll
        for (int k = 0; k < 6; ++k) {
            const int d = 1 << k;
            const float ur = __shfl_up(Sr, d, 64);
            const float ui = __shfl_up(Si, d, 64);
            if (lane >= d) {
                const float nr = fmaf(Mor[k], ur, fmaf(-Moi[k], ui, Sr));
                const float ni = fmaf(Mor[k], ui, fmaf( Moi[k], ur, Si));
                Sr = nr; Si = ni;
            }
        }
        const float Tr = __shfl(Sr, 63, 64);
        const float Ti = __shfl(Si, 63, 64);
        float exr = __shfl_up(Sr, 1, 64);
        float exi = __shfl_up(Si, 1, 64);
        if (lane == 0) { exr = 0.f; exi = 0.f; }

        // exact seed entering this lane's 32-sample segment
        const float sr = fmaf(plr, Cr, fmaf(-pli, Ci, exr));
        const float si = fmaf(plr, Ci, fmaf( pli, Cr, exi));

        // correct + transpose through private ybuf slice (wave-local)
        float wr = fmaf(gr, sr, -(gi * si));    // w = g * seed
        float wi = fmaf(gi, sr,  (gr * si));
#pragma unroll
        for (int m = 0; m < 8; ++m) {
            float4 y;
            y.x = lz[m].x + wi;
            y.y = fmaf(gi,  wr, fmaf(gr,  wi, lz[m].y));
            y.z = fmaf(G2i, wr, fmaf(G2r, wi, lz[m].z));
            y.w = fmaf(G3i, wr, fmaf(G3r, wi, lz[m].w));
            *(float4*)&yw[4 * P(8 * lane + m)] = y;
            const float nwr = fmaf(G4r, wr, -(G4i * wi));
            const float nwi = fmaf(G4i, wr,  (G4r * wi));
            wr = nwr; wi = nwi;
        }
        // per-wave coalesced store (1 KB contiguous per instruction);
        // same-wave LDS write->read: compiler inserts the lgkmcnt wait.
        float* op = out + ((size_t)(b * NO + O)) * (size_t)N_SAMP
                        + n0 + s * 2048;
#pragma unroll
        for (int i = 0; i < 8; ++i) {
            const int q = 64 * i + lane;
            const float4 v = *(const float4*)&yw[4 * P(q)];
            *(float4*)(op + 4 * q) = v;
        }

        // carry: C = g^2048 * C + T
        const float nCr = fmaf(Mor[6], Cr, fmaf(-Moi[6], Ci, Tr));
        const float nCi = fmaf(Mor[6], Ci, fmaf( Moi[6], Cr, Ti));
        Cr = rfl(nCr); Ci = rfl(nCi);
    }
#undef STEP
#undef DSEL
#undef LDQ
}

__global__ __launch_bounds__(NT, 2)
void duh_kernel(const float* __restrict__ x, const float* __restrict__ lw,
                float* __restrict__ out)
{
    __shared__ float tile[TQ * 4];            // 32 KB
    __shared__ float ybuf[NO * 2048];         // 64 KB: 8 KB per wave
    const int c  = blockIdx.x;
    const int b  = blockIdx.y;
    const int n0 = c * LBLK;
    const int t  = threadIdx.x;
    const int wv   = t >> 6;
    const int lane = t & 63;
    const float* xb = x + (size_t)b * N_SAMP;
    float* yw = ybuf + wv * 2048;
    switch (wv) {                              // wave o <-> channel o
      case 0: duh_wave<0>(lw, xb, out, tile, yw, b, n0, t, lane); break;
      case 1: duh_wave<1>(lw, xb, out, tile, yw, b, n0, t, lane); break;
      case 2: duh_wave<2>(lw, xb, out, tile, yw, b, n0, t, lane); break;
      case 3: duh_wave<3>(lw, xb, out, tile, yw, b, n0, t, lane); break;
      case 4: duh_wave<4>(lw, xb, out, tile, yw, b, n0, t, lane); break;
      case 5: duh_wave<5>(lw, xb, out, tile, yw, b, n0, t, lane); break;
      case 6: duh_wave<6>(lw, xb, out, tile, yw, b, n0, t, lane); break;
      default:duh_wave<7>(lw, xb, out, tile, yw, b, n0, t, lane); break;
    }
}

extern "C" void kernel_launch(void* const* d_in, const int* in_sizes, int n_in,
                              void* d_out, int out_size, void* d_ws, size_t ws_size,
                              hipStream_t stream) {
    const float* x  = (const float*)d_in[0];
    const float* lw = (const float*)d_in[1];
    float* out = (float*)d_out;

    dim3 grid(N_SAMP / LBLK, NB);   // 16 chunks x 16 batches = 256 blocks
    duh_kernel<<<grid, dim3(NT), 0, stream>>>(x, lw, out);
}

// Round 23
// 16.814 us; speedup vs baseline: 1.0402x; 1.0402x over previous
//
#include <hip/hip_runtime.h>
#include <math.h>

// Duhamel layer == per-channel causal FIR, h[q] = (1/wD) r^q sin(q*theta).
// Exact one-stream form: e[k] = (x[k] - g^W x[k-W])/wD;  Z = g Z + e;  y = Im Z.
// FINAL (r15 structure; best measured 16.48-16.69 us across 3 runs):
// ALL-CHANNELS-ONE-STAGE + WAVE-AUTONOMOUS STORES:
//   block = (batch, 4096-chunk): stage x window ONCE (32 KB, swizzled);
//   wave o = channel o with per-channel halo (alpha*H >= 5.1);
//   2 sub-rounds x 2048 outputs: IIR (32/lane, lz in regs) -> wave shfl scan
//   -> exact seed -> correction fused -> transpose via PRIVATE 8 KB ybuf
//   slice (wave-local, no block barrier) -> per-wave coalesced 1 KB stores.
//   Single __syncthreads (after stage).  256 blocks = 1/CU, one generation.

#define N_SAMP  65536
#define NB      16
#define NO      8
#define NT      512
#define LBLK    4096          // outputs per block per channel
#define LOOKB   3904          // ch0 halo 2048 + 1844 rounded to mult 32
#define TQ      2000          // tile quads (8000 floats = 32 KB)

constexpr int CW[NO]  = {1844, 1317, 1024, 768, 576, 419, 307, 230};
// per-lane halo samples (mult of 4): alpha*64*hseg >= 5.1 per channel
constexpr int CHS[NO] = {32, 24, 20, 16, 12, 8, 8, 4};

// XOR quad swizzle (involution within 8-quad groups): breaks stride-bank
// alignment of per-lane quad access.
__device__ __forceinline__ int P(int q) { return q ^ ((q >> 3) & 7); }

__device__ __forceinline__ float rfl(float x) {
    return __int_as_float(__builtin_amdgcn_readfirstlane(__float_as_int(x)));
}

template<int O>
__device__ __forceinline__ void duh_wave(const float* __restrict__ lw,
                                         float* __restrict__ out,
                                         const float* __restrict__ tile,
                                         float* __restrict__ yw,   // 8KB slice
                                         int b, int n0, int lane)
{
    constexpr int W  = CW[O];
    constexpr int Wu = (W + 3) & ~3;
    constexpr int E  = Wu - W;               // 0..3 intra-quad shift
    constexpr int QW = Wu / 4;               // delayed quad offset
    constexpr int HS = CHS[O];               // halo samples per lane
    constexpr int HQ = HS / 4;               // halo quads per lane

    // ---- per-wave channel constants (fast transcendentals) -> SGPR ---------
    const float omf  = fminf(fmaxf(__expf(lw[O]), 0.01f), 1000.0f);
    const float omD  = omf * 0.99874921777190895f;    // sqrt(1-0.05^2)
    const float th   = omD * 0.01f;
    const float alph = 0.0005f * omf;
    const float r1   = __expf(-alph);
    const float gr = rfl(r1 * __cosf(th)), gi = rfl(r1 * __sinf(th));   // g
    const float rW   = __expf(-alph * (float)W);
    const float aW   = th * (float)W;
    const float binv = 1.0f / omD;
    const float c1   = rfl(binv);
    const float c2   = rfl(binv * rW * __cosf(aW));    //  binv*Re g^W
    const float cei  = rfl(-binv * rW * __sinf(aW));   // -binv*Im g^W

    // G2..G4 for store correction
    float g2r_ = gr*gr - gi*gi,         g2i_ = 2.f*gr*gi;
    float g3r_ = g2r_*gr - g2i_*gi,     g3i_ = g2r_*gi + g2i_*gr;
    float g4r_ = g2r_*g2r_ - g2i_*g2i_, g4i_ = 2.f*g2r_*g2i_;
    const float G2r = rfl(g2r_), G2i = rfl(g2i_);
    const float G3r = rfl(g3r_), G3i = rfl(g3i_);
    const float G4r = rfl(g4r_), G4i = rfl(g4i_);

    // Mo[k] = g^(32*2^k) k=0..6  (out scan; Mo[6] = g^2048 carry multiplier)
    float Mor[7], Moi[7];
    {
        const float rl = __expf(-alph * 32.f);
        const float al = th * 32.f;
        float pr = rl * __cosf(al), pq = rl * __sinf(al);
#pragma unroll
        for (int k = 0; k < 7; ++k) {
            Mor[k] = rfl(pr); Moi[k] = rfl(pq);
            const float nr = pr*pr - pq*pq, ni = 2.f*pr*pq;
            pr = nr; pq = ni;
        }
    }
    // Mh[k] = g^(HS*2^k) k=0..5  (halo scan)
    float Mhr[6], Mhi[6];
    {
        const float rl = __expf(-alph * (float)HS);
        const float al = th * (float)HS;
        float pr = rl * __cosf(al), pq = rl * __sinf(al);
#pragma unroll
        for (int k = 0; k < 6; ++k) {
            Mhr[k] = rfl(pr); Mhi[k] = rfl(pq);
            const float nr = pr*pr - pq*pq, ni = 2.f*pr*pq;
            pr = nr; pq = ni;
        }
    }
    // pl = g^(32*lane)
    float plr = 1.f, pli = 0.f;
#pragma unroll
    for (int k = 0; k < 6; ++k) {
        if ((lane >> k) & 1) {
            const float nr = plr*Mor[k] - pli*Moi[k];
            const float ni = plr*Moi[k] + pli*Mor[k];
            plr = nr; pli = ni;
        }
    }

#define LDQ(q) (*(const float4*)&tile[4 * P(q)])
#define DSEL(e0,e1,e2,e3,d0,dn)                                              \
    if constexpr (E == 0)      { e0=d0.x; e1=d0.y; e2=d0.z; e3=d0.w; }       \
    else if constexpr (E == 1) { e0=d0.y; e1=d0.z; e2=d0.w; e3=dn.x; }       \
    else if constexpr (E == 2) { e0=d0.z; e1=d0.w; e2=dn.x; e3=dn.y; }       \
    else                       { e0=d0.w; e1=dn.x; e2=dn.y; e3=dn.z; }
#define STEP(xa, xc)                                              \
    {                                                             \
        const float er = fmaf(-c2, (xc), c1 * (xa));              \
        const float ei = cei * (xc);                              \
        const float nr = fmaf(gr, Br, fmaf(-gi, Bi, er));         \
        const float ni = fmaf(gi, Br, fmaf( gr, Bi, ei));         \
        Br = nr; Bi = ni;                                         \
    }

    // ---------------- halo: HS samples/lane, total only ---------------------
    float Cr, Ci;
    {
        float Br = 0.f, Bi = 0.f;
        const int q1 = 976 - 16 * HS + HQ * lane;   // covers [n0-64*HS, n0)
        const int q2 = q1 - QW;
        float4 d0 = LDQ(q2);
#pragma unroll
        for (int m = 0; m < HQ; ++m) {
            const float4 s1 = LDQ(q1 + m);
            const float4 dn = LDQ(q2 + m + 1);
            float e0, e1, e2, e3;
            DSEL(e0, e1, e2, e3, d0, dn);
            STEP(s1.x, e0); STEP(s1.y, e1); STEP(s1.z, e2); STEP(s1.w, e3);
            d0 = dn;
        }
        float Sr = Br, Si = Bi;
#pragma unroll
        for (int k = 0; k < 6; ++k) {
            const int d = 1 << k;
            const float ur = __shfl_up(Sr, d, 64);
            const float ui = __shfl_up(Si, d, 64);
            if (lane >= d) {
                const float nr = fmaf(Mhr[k], ur, fmaf(-Mhi[k], ui, Sr));
                const float ni = fmaf(Mhr[k], ui, fmaf( Mhi[k], ur, Si));
                Sr = nr; Si = ni;
            }
        }
        Cr = rfl(__shfl(Sr, 63, 64));       // exact state at n0 (zero-seeded)
        Ci = rfl(__shfl(Si, 63, 64));
    }

    // ---------------- 2 out sub-rounds x 2048 samples -----------------------
#pragma unroll
    for (int s = 0; s < 2; ++s) {
        const int q1 = 976 + 512 * s + 8 * lane;
        const int q2 = q1 - QW;

        float4 lz[8];
        float Br = 0.f, Bi = 0.f;
        float4 d0 = LDQ(q2);
#pragma unroll
        for (int m = 0; m < 8; ++m) {
            const float4 s1 = LDQ(q1 + m);
            const float4 dn = LDQ(q2 + m + 1);
            float e0, e1, e2, e3;
            DSEL(e0, e1, e2, e3, d0, dn);
            float4 lq;
            STEP(s1.x, e0); lq.x = Bi;
            STEP(s1.y, e1); lq.y = Bi;
            STEP(s1.z, e2); lq.z = Bi;
            STEP(s1.w, e3); lq.w = Bi;
            lz[m] = lq;
            d0 = dn;
        }

        // wave inclusive affine scan (segment mult g^32)
        float Sr = Br, Si = Bi;
#pragma unroll
        for (int k = 0; k < 6; ++k) {
            const int d = 1 << k;
            const float ur = __shfl_up(Sr, d, 64);
            const float ui = __shfl_up(Si, d, 64);
            if (lane >= d) {
                const float nr = fmaf(Mor[k], ur, fmaf(-Moi[k], ui, Sr));
                const float ni = fmaf(Mor[k], ui, fmaf( Moi[k], ur, Si));
                Sr = nr; Si = ni;
            }
        }
        const float Tr = __shfl(Sr, 63, 64);
        const float Ti = __shfl(Si, 63, 64);
        float exr = __shfl_up(Sr, 1, 64);
        float exi = __shfl_up(Si, 1, 64);
        if (lane == 0) { exr = 0.f; exi = 0.f; }

        // exact seed entering this lane's 32-sample segment
        const float sr = fmaf(plr, Cr, fmaf(-pli, Ci, exr));
        const float si = fmaf(plr, Ci, fmaf( pli, Cr, exi));

        // correct + transpose through private ybuf slice (wave-local)
        float wr = fmaf(gr, sr, -(gi * si));    // w = g * seed
        float wi = fmaf(gi, sr,  (gr * si));
#pragma unroll
        for (int m = 0; m < 8; ++m) {
            float4 y;
            y.x = lz[m].x + wi;
            y.y = fmaf(gi,  wr, fmaf(gr,  wi, lz[m].y));
            y.z = fmaf(G2i, wr, fmaf(G2r, wi, lz[m].z));
            y.w = fmaf(G3i, wr, fmaf(G3r, wi, lz[m].w));
            *(float4*)&yw[4 * P(8 * lane + m)] = y;
            const float nwr = fmaf(G4r, wr, -(G4i * wi));
            const float nwi = fmaf(G4i, wr,  (G4r * wi));
            wr = nwr; wi = nwi;
        }
        // per-wave coalesced store (1 KB contiguous per instruction);
        // same-wave LDS write->read: compiler inserts the lgkmcnt wait.
        float* op = out + ((size_t)(b * NO + O)) * (size_t)N_SAMP
                        + n0 + s * 2048;
#pragma unroll
        for (int i = 0; i < 8; ++i) {
            const int q = 64 * i + lane;
            const float4 v = *(const float4*)&yw[4 * P(q)];
            *(float4*)(op + 4 * q) = v;
        }

        // carry: C = g^2048 * C + T
        const float nCr = fmaf(Mor[6], Cr, fmaf(-Moi[6], Ci, Tr));
        const float nCi = fmaf(Mor[6], Ci, fmaf( Moi[6], Cr, Ti));
        Cr = rfl(nCr); Ci = rfl(nCi);
    }
#undef STEP
#undef DSEL
#undef LDQ
}

__global__ __launch_bounds__(NT, 2)
void duh_kernel(const float* __restrict__ x, const float* __restrict__ lw,
                float* __restrict__ out)
{
    __shared__ float tile[TQ * 4];            // 32 KB
    __shared__ float ybuf[NO * 2048];         // 64 KB: 8 KB per wave
    const int c  = blockIdx.x;
    const int b  = blockIdx.y;
    const int n0 = c * LBLK;
    const int t  = threadIdx.x;

    // ---- cooperative coalesced stage: [n0-3904, n0+4096) -------------------
    const float* xb = x + (size_t)b * N_SAMP;
    const int tstart = n0 - LOOKB;
#pragma unroll
    for (int i = 0; i < 4; ++i) {
        const int k = t + 512 * i;
        if (k < TQ) {
            const int g0 = tstart + 4 * k;    // mult of 4; quad fully in/out
            float4 v;
            if (g0 >= 0) v = *(const float4*)(xb + g0);
            else { v.x = 0.f; v.y = 0.f; v.z = 0.f; v.w = 0.f; }
            *(float4*)&tile[4 * P(k)] = v;
        }
    }
    __syncthreads();                           // the ONLY block barrier

    const int wv   = t >> 6;
    const int lane = t & 63;
    float* yw = ybuf + wv * 2048;
    switch (wv) {                              // wave o <-> channel o
      case 0: duh_wave<0>(lw, out, tile, yw, b, n0, lane); break;
      case 1: duh_wave<1>(lw, out, tile, yw, b, n0, lane); break;
      case 2: duh_wave<2>(lw, out, tile, yw, b, n0, lane); break;
      case 3: duh_wave<3>(lw, out, tile, yw, b, n0, lane); break;
      case 4: duh_wave<4>(lw, out, tile, yw, b, n0, lane); break;
      case 5: duh_wave<5>(lw, out, tile, yw, b, n0, lane); break;
      case 6: duh_wave<6>(lw, out, tile, yw, b, n0, lane); break;
      default:duh_wave<7>(lw, out, tile, yw, b, n0, lane); break;
    }
}

extern "C" void kernel_launch(void* const* d_in, const int* in_sizes, int n_in,
                              void* d_out, int out_size, void* d_ws, size_t ws_size,
                              hipStream_t stream) {
    const float* x  = (const float*)d_in[0];
    const float* lw = (const float*)d_in[1];
    float* out = (float*)d_out;

    dim3 grid(N_SAMP / LBLK, NB);   // 16 chunks x 16 batches = 256 blocks
    duh_kernel<<<grid, dim3(NT), 0, stream>>>(x, lw, out);
}